// Round 2
// 181.901 us; speedup vs baseline: 1.0070x; 1.0070x over previous
//
#include <hip/hip_runtime.h>

// SimpleRNN hidden=1: h_t = tanh(a*x_t + b*h_{t-1} + c), out = h_T per row.
// B=8192 rows x T=4096 steps, x fp32 [B,T] row-major.
//
// R7 structure (re-submitted R8 — R7 bench died on container failure, not
// kernel fault): one 256-thread block per row; thread t owns chunk t
// (256 chunks x 16 steps). vs R6: staging is WAVE-PRIVATE — wave w
// stages exactly the 4 KiB region it will read back (fx4 s in
// [256w, 256w+256)), so the block-wide __syncthreads() after staging is
// GONE. Wave w's lanes read s = 4t+q with t = 64w+lane, i.e. s in
// [256w, 256w+256); the XOR swizzle phys = s ^ ((s>>2)&7) only touches
// bits 0..2 of s, so it never leaves a 256-fx4 region -> waves are fully
// independent in LDS. Same-wave ds_write -> ds_read ordering is enforced
// by the compiler's lgkmcnt waits; no barrier needed. Each wave starts
// its chunk scan as soon as ITS 4 loads land (no 4-wave vmcnt(0) convoy).
//
// Staging coalescing: s = w*256 + i*64 + lane -> 64 lanes x 16 B
// consecutive = 1 KiB per instruction, 4 instructions cover a contiguous
// 4 KiB span per wave. NT loads: x is single-use -> no cache allocation.
//
// Swizzle conflict analysis (unchanged from R6 — the base w*256 + i*64 is
// congruent 0 mod 8 in both (s&7) and ((s>>2)&7)):
//   write s = base+lane: quad = (lane&7)^((lane>>2)&7) -> 8 distinct / 8 lanes
//   read  s = 4t+q     : quad = (4(t&1)+q)^(t&7)       -> 8 distinct / 8 lanes
//
// Math (absmax 0.0 in prior rounds): E = exp(2t); r = rcp(E+1); h = 1-2r;
//   E' = exp2(fma(r, nB4, q)), q = fma(x, A2, C2).
// Per chunk from h=0: G = chunk output, P = dF/dh|_0 = prod b*sech^2
// (post-step states; first pre-state factor skipped, final added at tail).
// Combine: affine maps compose associatively -> 6-step intra-wave shfl scan,
// then thread 0 composes the 4 wave totals (temporal order w=0..3) after the
// single remaining (cheap) barrier.

constexpr int T_LEN = 4096;
constexpr int NTHR  = 256;
constexpr int CH    = T_LEN / NTHR;   // 16 steps per thread-chunk
constexpr int NF4   = CH / 4;         // 4 float4 per thread

typedef float fx4 __attribute__((ext_vector_type(4)));

__device__ __forceinline__ int swz(int s) { return s ^ ((s >> 2) & 7); }

#define STEP_PG(qv)                                                     \
    do {                                                                \
        float r_ = __builtin_amdgcn_rcpf(E + 1.0f);                     \
        P *= (fourb * r_) * (1.0f - r_);                                \
        E = __builtin_amdgcn_exp2f(fmaf(r_, nB4, (qv)));                \
    } while (0)

__global__ __launch_bounds__(NTHR)
void rnn_row_kernel(const float* __restrict__ x,
                    const float* __restrict__ w_ih,
                    const float* __restrict__ w_hh,
                    const float* __restrict__ b_ih,
                    const float* __restrict__ b_hh,
                    float* __restrict__ out) {
    __shared__ fx4 sm[T_LEN / 4];          // 16 KiB: one row
    __shared__ float wP[4], wG[4];         // per-wave affine totals

    const int tid  = threadIdx.x;
    const int lane = tid & 63;
    const int wv   = tid >> 6;
    const int row  = blockIdx.x;

    const float a  = w_ih[0];
    const float bb = w_hh[0];
    const float cc = b_ih[0] + b_hh[0];

    const float L2E2  = 2.88539008177792681472f;   // 2*log2(e)
    const float A2    = a * L2E2;
    const float C2    = (bb + cc) * L2E2;
    const float nB4   = -(bb * L2E2 * 2.0f);       // -4b*log2(e)
    const float fourb = 4.0f * bb;

    // --- Stage: wave-private, 4 coalesced NT dwordx4 per thread ---
    // Wave w covers fx4 indices [256w, 256w+256) = its own read region.
    const fx4* xp = (const fx4*)(x + (size_t)row * T_LEN);
#pragma unroll
    for (int i = 0; i < 4; ++i) {
        int s = (wv << 8) + (i << 6) + lane;
        sm[swz(s)] = __builtin_nontemporal_load(&xp[s]);
    }
    // NO __syncthreads(): each wave reads back only LDS it wrote itself;
    // program order + lgkmcnt give the ordering within a wave.

    // --- Gather own 16-step chunk: 4 x ds_read_b128, 8-phase clean ---
    fx4 buf[NF4];
#pragma unroll
    for (int q = 0; q < NF4; ++q) buf[q] = sm[swz(tid * NF4 + q)];

    // --- 16-step chunk scan from h=0 with exact gain product ---
    float E, P = 1.0f;
    {
        fx4 v = buf[0];
        float q0 = fmaf(v.x, A2, C2);
        float q1 = fmaf(v.y, A2, C2);
        float q2 = fmaf(v.z, A2, C2);
        float q3 = fmaf(v.w, A2, C2);
        E = __builtin_amdgcn_exp2f(fmaf(0.5f, nB4, q0));  // h=0 => r=0.5 exact
        STEP_PG(q1); STEP_PG(q2); STEP_PG(q3);
    }
#pragma unroll
    for (int i = 1; i < NF4; ++i) {
        fx4 v = buf[i];
        float q0 = fmaf(v.x, A2, C2);
        float q1 = fmaf(v.y, A2, C2);
        float q2 = fmaf(v.z, A2, C2);
        float q3 = fmaf(v.w, A2, C2);
        STEP_PG(q0); STEP_PG(q1); STEP_PG(q2); STEP_PG(q3);
    }
    float r = __builtin_amdgcn_rcpf(E + 1.0f);
    float G = fmaf(-2.0f, r, 1.0f);
    P *= (fourb * r) * (1.0f - r);

    // --- Intra-wave inclusive affine scan (chunk order = lane order) ---
#pragma unroll
    for (int d = 1; d < 64; d <<= 1) {
        float Pl = __shfl_up(P, d, 64);
        float Gl = __shfl_up(G, d, 64);
        if (lane >= d) {
            G = fmaf(P, Gl, G);
            P *= Pl;
        }
    }
    if (lane == 63) { wP[wv] = P; wG[wv] = G; }
    __syncthreads();

    // --- Cross-wave composition, temporal order w=0..3; h0 = 0 ---
    if (tid == 0) {
        float h = wG[0];
        h = fmaf(wP[1], h, wG[1]);
        h = fmaf(wP[2], h, wG[2]);
        h = fmaf(wP[3], h, wG[3]);
        out[row] = h;
    }
}

extern "C" void kernel_launch(void* const* d_in, const int* in_sizes, int n_in,
                              void* d_out, int out_size, void* d_ws, size_t ws_size,
                              hipStream_t stream) {
    const float* x    = (const float*)d_in[0];
    const float* w_ih = (const float*)d_in[1];
    const float* w_hh = (const float*)d_in[2];
    const float* b_ih = (const float*)d_in[3];
    const float* b_hh = (const float*)d_in[4];
    float* out = (float*)d_out;

    const int B = out_size;                 // 8192 rows, one block per row
    dim3 grid(B), block(NTHR);
    rnn_row_kernel<<<grid, block, 0, stream>>>(x, w_ih, w_hh, b_ih, b_hh, out);
}